// Round 7
// baseline (239.542 us; speedup 1.0000x reference)
//
#include <hip/hip_runtime.h>
#include <hip/hip_bf16.h>
#include <math.h>
#include <stdint.h>

// Problem constants (B=2, S=2048 -> T=4096 tokens)
#define TOKENS 4096
#define HDIM   768
#define FFDIM  1536
#define NEXP   8
#define GEMM_GRID 512   // 64 slots per bucket; id%8 = bucket -> XCD affinity
#define SLOTS (GEMM_GRID / 8)

typedef __attribute__((ext_vector_type(8))) short bf16x8;   // 8 bf16 = 4 VGPRs
typedef __attribute__((ext_vector_type(4))) float f32x4;    // MFMA accumulator

// round-to-nearest-even f32 -> bf16 (bit pattern)
__device__ __forceinline__ unsigned short f2bf(float f) {
    union { float f; uint32_t u; } c; c.f = f;
    uint32_t u = c.u;
    uint32_t r = (u + 0x7FFFu + ((u >> 16) & 1u)) >> 16;
    return (unsigned short)r;
}

// async global->LDS, 16B per lane; LDS dest is wave-uniform base + lane*16
__device__ __forceinline__ void gload_lds16(const void* g, void* l) {
    __builtin_amdgcn_global_load_lds(
        (const __attribute__((address_space(1))) void*)g,
        (__attribute__((address_space(3))) void*)l, 16, 0, 0);
}

// ---------------------------------------------------------------------------
// MERGED cast + gating (r6): blocks 0..1023 do gating (one wave per token,
// fp32 logits, top-2 softmax, bf16 cast of x, outp zeroing); blocks
// 1024..3071 stream-cast both weight tensors to bf16. NO atomics (r2:
// contended atomics serialized to 102 us).
__global__ __launch_bounds__(256) void cast_gate(
    const float* __restrict__ x, const float* __restrict__ gw,
    const float* __restrict__ wfc, const float* __restrict__ wproj,
    unsigned short* __restrict__ wfc_bf, unsigned short* __restrict__ wpj_bf,
    float* __restrict__ logits,
    int* __restrict__ tok_e, float* __restrict__ tok_g,
    unsigned short* __restrict__ x_bf, float* __restrict__ outp, int n4)
{
    if (blockIdx.x >= 1024) {
        // ---- weight cast arm (2048 blocks)
        int stride = 2048 * 256;
        for (int i = (blockIdx.x - 1024) * 256 + threadIdx.x; i < 2 * n4; i += stride) {
            const float4* s = (i < n4) ? (const float4*)wfc : (const float4*)wproj;
            ushort4* d = (i < n4) ? (ushort4*)wfc_bf : (ushort4*)wpj_bf;
            int j = (i < n4) ? i : i - n4;
            float4 v = s[j];
            ushort4 o;
            o.x = f2bf(v.x); o.y = f2bf(v.y); o.z = f2bf(v.z); o.w = f2bf(v.w);
            d[j] = o;
        }
        return;
    }
    // ---- gating arm (1024 blocks)
    // zero outp: 786432 float4 over 1024 blocks = 3 per thread
    float4 zz = make_float4(0.f, 0.f, 0.f, 0.f);
#pragma unroll
    for (int j = 0; j < 3; j++)
        ((float4*)outp)[blockIdx.x * 768 + j * 256 + threadIdx.x] = zz;

    int t = blockIdx.x * 4 + (threadIdx.x >> 6);
    int lane = threadIdx.x & 63;
    const float4* xt = (const float4*)(x + (size_t)t * HDIM);   // 192 float4/token
    const float4* gw4 = (const float4*)gw;                      // [E][192]
    ushort4* xbt = (ushort4*)(x_bf + (size_t)t * HDIM);
    float acc[NEXP];
#pragma unroll
    for (int e = 0; e < NEXP; e++) acc[e] = 0.f;
#pragma unroll
    for (int it = 0; it < 3; it++) {
        int i = lane + it * 64;
        float4 xv = xt[i];
        ushort4 o;
        o.x = f2bf(xv.x); o.y = f2bf(xv.y); o.z = f2bf(xv.z); o.w = f2bf(xv.w);
        xbt[i] = o;
#pragma unroll
        for (int e = 0; e < NEXP; e++) {
            float4 wv = gw4[e * 192 + i];
            acc[e] += xv.x * wv.x + xv.y * wv.y + xv.z * wv.z + xv.w * wv.w;
        }
    }
#pragma unroll
    for (int e = 0; e < NEXP; e++) {
#pragma unroll
        for (int off = 32; off > 0; off >>= 1)
            acc[e] += __shfl_xor(acc[e], off);
    }
    if (lane == 0) {
        float4 l0 = make_float4(acc[0], acc[1], acc[2], acc[3]);
        float4 l1 = make_float4(acc[4], acc[5], acc[6], acc[7]);
        float4* lp = (float4*)(logits + (size_t)t * NEXP);
        lp[0] = l0; lp[1] = l1;
        int i0 = 0; float v0 = acc[0];
#pragma unroll
        for (int e = 1; e < NEXP; e++) if (acc[e] > v0) { v0 = acc[e]; i0 = e; }
        int i1 = -1; float v1 = -3.4e38f;
#pragma unroll
        for (int e = 0; e < NEXP; e++) if (e != i0 && acc[e] > v1) { v1 = acc[e]; i1 = e; }
        float g0 = 1.f / (1.f + expf(v1 - v0));   // softmax over top-2 (v0 >= v1)
        tok_e[t * 2] = i0; tok_e[t * 2 + 1] = i1;
        tok_g[t * 2] = g0; tok_g[t * 2 + 1] = 1.f - g0;
    }
}

// ---------------------------------------------------------------------------
// Build per-expert routed lists deterministically (no global atomics).
// Single block, 1024 threads (16 waves), 8 (token,k) entries per thread.
// Per-wave __shfl_up u64 scan + 16-wave fixup. GEMMs derive geometry from
// counts[8].
__global__ __launch_bounds__(1024) void build_lists(
    const int* __restrict__ tok_e, const float* __restrict__ tok_g,
    int* __restrict__ counts,
    int* __restrict__ entries, float* __restrict__ gates)
{
    __shared__ unsigned long long wlo[16], whi[16];
    int tid = threadIdx.x;
    int lane = tid & 63, wid = tid >> 6;

    int eL[8]; float gL[8];
    int4 ea = ((const int4*)tok_e)[tid * 2];
    int4 eb = ((const int4*)tok_e)[tid * 2 + 1];
    float4 ga = ((const float4*)tok_g)[tid * 2];
    float4 gb = ((const float4*)tok_g)[tid * 2 + 1];
    eL[0] = ea.x; eL[1] = ea.y; eL[2] = ea.z; eL[3] = ea.w;
    eL[4] = eb.x; eL[5] = eb.y; eL[6] = eb.z; eL[7] = eb.w;
    gL[0] = ga.x; gL[1] = ga.y; gL[2] = ga.z; gL[3] = ga.w;
    gL[4] = gb.x; gL[5] = gb.y; gL[6] = gb.z; gL[7] = gb.w;

    unsigned long long clo = 0, chi = 0;
#pragma unroll
    for (int j = 0; j < 8; j++) {
        int e = eL[j];
        unsigned long long one = 1ull << ((e & 3) * 16);
        if (e < 4) clo += one; else chi += one;
    }
    unsigned long long ilo = clo, ihi = chi;
#pragma unroll
    for (int s = 1; s < 64; s <<= 1) {
        unsigned long long t1 = __shfl_up(ilo, s);
        unsigned long long t2 = __shfl_up(ihi, s);
        if (lane >= s) { ilo += t1; ihi += t2; }
    }
    if (lane == 63) { wlo[wid] = ilo; whi[wid] = ihi; }
    __syncthreads();
    if (tid == 0) {
        unsigned long long rl = 0, rh = 0;
#pragma unroll
        for (int i = 0; i < 16; i++) {
            unsigned long long a = wlo[i], b = whi[i];
            wlo[i] = rl; whi[i] = rh;   // exclusive wave prefix
            rl += a; rh += b;
        }
#pragma unroll
        for (int e = 0; e < 4; e++) {
            counts[e]     = (int)((rl >> (e * 16)) & 0xFFFF);
            counts[e + 4] = (int)((rh >> (e * 16)) & 0xFFFF);
        }
    }
    __syncthreads();
    unsigned long long rlo = wlo[wid] + (ilo - clo);   // exclusive thread prefix
    unsigned long long rhi = whi[wid] + (ihi - chi);
#pragma unroll
    for (int j = 0; j < 8; j++) {
        int e = eL[j];
        int sh = (e & 3) * 16;
        unsigned long long one = 1ull << sh;
        int slot;
        if (e < 4) { slot = (int)((rlo >> sh) & 0xFFFF); rlo += one; }
        else       { slot = (int)((rhi >> sh) & 0xFFFF); rhi += one; }
        entries[e * TOKENS + slot] = tid * 8 + j;   // = t*2+k
        gates[e * TOKENS + slot]   = gL[j];
    }
}

// ---------------------------------------------------------------------------
// Routed GEMM, r7: MAX-DENSITY BIG-TILE @ 1 blk/CU.
// r4->r6 showed per-phase MFMA density tracks perf (density 16: 65/55 us,
// density 32: 51 us) and the per-CU LDS-fill rate (~64 B/cyc through the
// global_load_lds path) vs per-phase MFMA work caps MfmaUtil. So: raise
// density to the LDS limit and accept 1 block/CU (m201/HK operating point:
// 512 thr, >=96KB LDS, 1 blk/CU, 62% MfmaUtil precedent; 80KB static LDS
// already proven to run in r5/r6).
//   GEMM1: BM=256 x TN=256, BK=64 -> 128KB LDS, 64 MFMA/wave/phase,
//          12 phases, items = rts*6 (~192-240) <= 256 CUs -> single span.
//   GEMM2: BM=256 x TN=128, BK=64 -> 96KB LDS, 32 MFMA/wave/phase,
//          24 phases, items = rts*6 (~192-240) -> single span.
// T4 counted-vmcnt double-buffer (r5 schedule, unchanged): vmcnt(NV) never
// 0 in-loop; WAR safe (buffer re-staged only after the barrier following
// its compute). 8 waves in 4x2. Early-exit before the full counts read so
// the ~280 exiting blocks drain in the background of the active span.
// LDS rows 128B = 8x16B segs, XOR swizzle seg^(row&7): ds_read_b128
// bank-uniform, 0 conflicts (verified r6). Geometry from counts[8];
// bucket == expert (XCD-affine under round-robin dispatch).
template<int KD, int ND, int BK, int TN, int NCTP, bool IS_FC>
__global__ __launch_bounds__(512) void moe_gemm(
    const unsigned short* __restrict__ Asrc,
    const unsigned short* __restrict__ Bsrc,    // [E][ND][KD] (B^T form)
    const int* __restrict__ counts,
    const int* __restrict__ entries,
    const float* __restrict__ gates,
    unsigned short* __restrict__ hmid,
    float* __restrict__ outp)
{
    constexpr int BM = 256;
    constexpr int AJ = TN / 32;         // col frags per wave (8 or 4)
    constexpr int S  = BK / 8;          // 16B segs per row (8)
    constexpr int RPC = 64 / S;         // rows covered per gload call (8)
    constexpr int LS  = (S == 8) ? 3 : 2;
    constexpr int SH  = (S == 8) ? 0 : 1;
    constexpr int MK  = S - 1;
    constexpr int ACAL = 32 / RPC;      // A gload calls per wave (4)
    constexpr int BCAL = (TN / 8) / RPC;// B gload calls per wave (4 or 2)
    constexpr int NV   = ACAL + BCAL;   // in-flight budget per stage (8 or 6)
    constexpr int SS   = BK / 32;       // MFMA K-halves per phase (2)

    int bkt  = blockIdx.x & 7;         // bucket == expert
    int slot = blockIdx.x >> 3;        // 0..SLOTS-1

    // early exit needs only this bucket's count (exiters drain fast)
    int n_e = counts[bkt];
    int rts = (n_e + BM - 1) >> 8;
    int nfill = rts * NCTP;
    if (slot >= nfill) return;
    int ebase = 0;
#pragma unroll
    for (int e = 0; e < NEXP; e++) { int c = counts[e]; if (e < bkt) ebase += c; }
    const int* lst = entries + bkt * TOKENS;

    int tid = threadIdx.x;
    int w = tid >> 6;          // wave 0..7
    int l = tid & 63;          // lane
    int sg = l & MK;           // seg staged by this lane
    int lr = l >> LS;          // row-within-call staged by this lane
    int lo = l & 15;
    int q  = l >> 4;
    int wr = w >> 1, wc = w & 1;   // 4x2 wave grid: 64 rows x TN/2 cols each

    __shared__ __align__(16) unsigned short sA[2 * BM * BK];
    __shared__ __align__(16) unsigned short sB[2 * TN * BK];
    unsigned short* sA0 = sA;
    unsigned short* sA1 = sA + BM * BK;   // compile-time offsets (static alias)
    unsigned short* sB0 = sB;
    unsigned short* sB1 = sB + TN * BK;

    // fragment LDS offsets (item-independent)
    int aOff[4][SS], bOff[AJ][SS];
#pragma unroll
    for (int i = 0; i < 4; i++) {
        int m = wr * 64 + i * 16 + lo;
#pragma unroll
        for (int s = 0; s < SS; s++)
            aOff[i][s] = m * BK + (((s * 4 + q) ^ ((m >> SH) & MK)) * 8);
    }
#pragma unroll
    for (int j = 0; j < AJ; j++) {
        int n = wc * (TN / 2) + j * 16 + lo;
#pragma unroll
        for (int s = 0; s < SS; s++)
            bOff[j][s] = n * BK + (((s * 4 + q) ^ ((n >> SH) & MK)) * 8);
    }

    for (int p = slot; p < nfill; p += SLOTS) {   // backstop stride; 1 iter typical
        int ct   = p / rts;
        int r    = p - ct * rts;
        int row0 = r << 8;
        int n0 = ct * TN;

        // ---- staging addresses: one gload call = 64 lanes x 16B = RPC rows.
        // Global k-seg for (row rr, LDS seg sg) is sg ^ ((rr>>SH)&MK).
        const unsigned short* Ag[ACAL];
        int aLds[ACAL];
#pragma unroll
        for (int c = 0; c < ACAL; c++) {
            int rr = w * 32 + c * RPC + lr;      // tile row 0..255
            int gr = row0 + rr;
            int id = gr < n_e ? gr : n_e - 1;    // clamp (discarded in epilogue)
            size_t arow = IS_FC ? (size_t)(lst[id] >> 1) : (size_t)(ebase + id);
            Ag[c] = Asrc + arow * KD + (size_t)((sg ^ ((rr >> SH) & MK)) * 8);
            aLds[c] = (w * 32 + c * RPC) * BK;   // wave-uniform chunk base
        }
        const unsigned short* Bg[BCAL];
        int bLds[BCAL];
#pragma unroll
        for (int c = 0; c < BCAL; c++) {
            int rr = w * (TN / 8) + c * RPC + lr; // tile row 0..TN-1
            Bg[c] = Bsrc + ((size_t)bkt * ND + n0 + rr) * KD + (size_t)((sg ^ ((rr >> SH) & MK)) * 8);
            bLds[c] = (w * (TN / 8) + c * RPC) * BK;
        }

        f32x4 acc[4][AJ];
#pragma unroll
        for (int i = 0; i < 4; i++)
#pragma unroll
            for (int j = 0; j < AJ; j++) acc[i][j] = (f32x4){0.f, 0.f, 0.f, 0.f};

        auto stage = [&](unsigned short* SA, unsigned short* SB, int k0) {
#pragma unroll
            for (int c = 0; c < ACAL; c++) gload_lds16(Ag[c] + k0, SA + aLds[c]);
#pragma unroll
            for (int c = 0; c < BCAL; c++) gload_lds16(Bg[c] + k0, SB + bLds[c]);
        };
        auto compute = [&](const unsigned short* SA, const unsigned short* SB) {
#pragma unroll
            for (int s = 0; s < SS; s++) {
                bf16x8 a[4], b[AJ];
#pragma unroll
                for (int i = 0; i < 4; i++) a[i] = *(const bf16x8*)(SA + aOff[i][s]);
#pragma unroll
                for (int j = 0; j < AJ; j++) b[j] = *(const bf16x8*)(SB + bOff[j][s]);
#pragma unroll
                for (int i = 0; i < 4; i++)
#pragma unroll
                    for (int j = 0; j < AJ; j++)
                        acc[i][j] = __builtin_amdgcn_mfma_f32_16x16x32_bf16(a[i], b[j], acc[i][j], 0, 0, 0);
            }
        };

        // T4 counted-vmcnt double-buffer, raw barriers; vmcnt(NV) retires the
        // older buffer's loads while the newest NV stay in flight.
#define WAITN asm volatile("s_waitcnt vmcnt(%0)" :: "n"(NV) : "memory")
#define WAIT0 asm volatile("s_waitcnt vmcnt(0)" ::: "memory")
        stage(sA0, sB0, 0);
        for (int k0 = 0; k0 < KD; k0 += 2 * BK) {   // KD/(2*BK) = 6 / 12 iters
            stage(sA1, sB1, k0 + BK);
            WAITN;
            __builtin_amdgcn_s_barrier();
            __builtin_amdgcn_s_setprio(1);
            compute(sA0, sB0);
            __builtin_amdgcn_s_setprio(0);
            __builtin_amdgcn_s_barrier();
            if (k0 + 2 * BK < KD) {
                stage(sA0, sB0, k0 + 2 * BK);
                WAITN;
            } else {
                WAIT0;
            }
            __builtin_amdgcn_s_barrier();
            __builtin_amdgcn_s_setprio(1);
            compute(sA1, sB1);
            __builtin_amdgcn_s_setprio(0);
            __builtin_amdgcn_s_barrier();
        }
#undef WAITN
#undef WAIT0

        // ---- epilogue (D: col=lo, row=q*4+rr)
#pragma unroll
        for (int i = 0; i < 4; i++) {
            int rowB = row0 + wr * 64 + i * 16 + q * 4;
#pragma unroll
            for (int rr = 0; rr < 4; rr++) {
                int orow = rowB + rr;
                if (orow < n_e) {
                    if (IS_FC) {
                        size_t hrow = (size_t)(ebase + orow);
#pragma unroll
                        for (int j = 0; j < AJ; j++) {
                            float v = acc[i][j][rr];
                            v = 0.5f * v * (1.f + erff(v * 0.70710678118654752f));  // exact gelu
                            hmid[hrow * ND + n0 + wc * (TN / 2) + j * 16 + lo] = f2bf(v);
                        }
                    } else {
                        int token = lst[orow] >> 1;
                        float g = gates[bkt * TOKENS + orow];
#pragma unroll
                        for (int j = 0; j < AJ; j++) {
                            atomicAdd(&outp[(size_t)token * ND + n0 + wc * (TN / 2) + j * 16 + lo],
                                      acc[i][j][rr] * g);
                        }
                    }
                }
            }
        }
    }
}

// ---------------------------------------------------------------------------
extern "C" void kernel_launch(void* const* d_in, const int* in_sizes, int n_in,
                              void* d_out, int out_size, void* d_ws, size_t ws_size,
                              hipStream_t stream) {
    const float* x     = (const float*)d_in[0];   // [T, H]
    const float* gw    = (const float*)d_in[1];   // [E, H]
    const float* wfc   = (const float*)d_in[2];   // [E, FF, H]
    const float* wproj = (const float*)d_in[3];   // [E, H, FF]
    float* outp   = (float*)d_out;                       // [T*H]
    float* logits = outp + (size_t)TOKENS * HDIM;        // [T*E]

    char* ws = (char*)d_ws;
    int*   counts  = (int*)ws;                            // 8 ints
    size_t off = 256;
    int*   entries = (int*)(ws + off);                    // [E][T]
    float* gates   = (float*)(ws + off + NEXP * TOKENS * 4);
    off += 2ull * NEXP * TOKENS * 4;
    int*   tok_e   = (int*)(ws + off);   off += (size_t)TOKENS * 2 * 4;
    float* tok_g   = (float*)(ws + off); off += (size_t)TOKENS * 2 * 4;
    unsigned short* x_bf   = (unsigned short*)(ws + off); off += (size_t)TOKENS * HDIM * 2;
    unsigned short* wfc_bf = (unsigned short*)(ws + off); off += (size_t)NEXP * FFDIM * HDIM * 2;
    unsigned short* wpj_bf = (unsigned short*)(ws + off); off += (size_t)NEXP * HDIM * FFDIM * 2;
    unsigned short* hmid   = (unsigned short*)(ws + off);        // [2T][FF] bf16, slot-compacted

    cast_gate<<<3072, 256, 0, stream>>>(x, gw, wfc, wproj, wfc_bf, wpj_bf,
                                        logits, tok_e, tok_g, x_bf, outp,
                                        NEXP * FFDIM * HDIM / 4);
    build_lists<<<1, 1024, 0, stream>>>(tok_e, tok_g, counts, entries, gates);
    moe_gemm<HDIM, FFDIM, 64, 256, FFDIM / 256, true ><<<GEMM_GRID, 512, 0, stream>>>(
        x_bf, wfc_bf, counts, entries, gates, hmid, outp);
    moe_gemm<FFDIM, HDIM, 64, 128, HDIM / 128,  false><<<GEMM_GRID, 512, 0, stream>>>(
        hmid, wpj_bf, counts, entries, gates, hmid, outp);
}

// Round 8
// 214.956 us; speedup vs baseline: 1.1144x; 1.1144x over previous
//
#include <hip/hip_runtime.h>
#include <hip/hip_bf16.h>
#include <math.h>
#include <stdint.h>

// Problem constants (B=2, S=2048 -> T=4096 tokens)
#define TOKENS 4096
#define HDIM   768
#define FFDIM  1536
#define NEXP   8

typedef __attribute__((ext_vector_type(8))) short bf16x8;   // 8 bf16 = 4 VGPRs
typedef __attribute__((ext_vector_type(4))) float f32x4;    // MFMA accumulator

// round-to-nearest-even f32 -> bf16 (bit pattern)
__device__ __forceinline__ unsigned short f2bf(float f) {
    union { float f; uint32_t u; } c; c.f = f;
    uint32_t u = c.u;
    uint32_t r = (u + 0x7FFFu + ((u >> 16) & 1u)) >> 16;
    return (unsigned short)r;
}

// async global->LDS, 16B per lane; LDS dest is wave-uniform base + lane*16
__device__ __forceinline__ void gload_lds16(const void* g, void* l) {
    __builtin_amdgcn_global_load_lds(
        (const __attribute__((address_space(1))) void*)g,
        (__attribute__((address_space(3))) void*)l, 16, 0, 0);
}

__device__ __forceinline__ void cast4(const float* __restrict__ s,
                                      unsigned short* __restrict__ d, int i) {
    float4 v = ((const float4*)s)[i];
    ushort4 o;
    o.x = f2bf(v.x); o.y = f2bf(v.y); o.z = f2bf(v.z); o.w = f2bf(v.w);
    ((ushort4*)d)[i] = o;
}

// ---------------------------------------------------------------------------
// Gating only (r8: weight casts moved into later dispatches to shorten the
// serial chain). One wave per token (4 tokens / 256-thread block). fp32
// logits (checked output!), top-2 softmax, NO atomics (r2: contended
// atomics serialized to 102 us). Fused: bf16 cast of x, zeroing of outp.
__global__ __launch_bounds__(256) void gating(
    const float* __restrict__ x, const float* __restrict__ gw,
    float* __restrict__ logits,
    int* __restrict__ tok_e, float* __restrict__ tok_g,
    unsigned short* __restrict__ x_bf, float* __restrict__ outp)
{
    // zero outp: 786432 float4 over 1024 blocks = 3 per thread
    float4 zz = make_float4(0.f, 0.f, 0.f, 0.f);
#pragma unroll
    for (int j = 0; j < 3; j++)
        ((float4*)outp)[blockIdx.x * 768 + j * 256 + threadIdx.x] = zz;

    int t = blockIdx.x * 4 + (threadIdx.x >> 6);
    int lane = threadIdx.x & 63;
    const float4* xt = (const float4*)(x + (size_t)t * HDIM);   // 192 float4/token
    const float4* gw4 = (const float4*)gw;                      // [E][192]
    ushort4* xbt = (ushort4*)(x_bf + (size_t)t * HDIM);
    float acc[NEXP];
#pragma unroll
    for (int e = 0; e < NEXP; e++) acc[e] = 0.f;
#pragma unroll
    for (int it = 0; it < 3; it++) {
        int i = lane + it * 64;
        float4 xv = xt[i];
        ushort4 o;
        o.x = f2bf(xv.x); o.y = f2bf(xv.y); o.z = f2bf(xv.z); o.w = f2bf(xv.w);
        xbt[i] = o;
#pragma unroll
        for (int e = 0; e < NEXP; e++) {
            float4 wv = gw4[e * 192 + i];
            acc[e] += xv.x * wv.x + xv.y * wv.y + xv.z * wv.z + xv.w * wv.w;
        }
    }
#pragma unroll
    for (int e = 0; e < NEXP; e++) {
#pragma unroll
        for (int off = 32; off > 0; off >>= 1)
            acc[e] += __shfl_xor(acc[e], off);
    }
    if (lane == 0) {
        float4 l0 = make_float4(acc[0], acc[1], acc[2], acc[3]);
        float4 l1 = make_float4(acc[4], acc[5], acc[6], acc[7]);
        float4* lp = (float4*)(logits + (size_t)t * NEXP);
        lp[0] = l0; lp[1] = l1;
        int i0 = 0; float v0 = acc[0];
#pragma unroll
        for (int e = 1; e < NEXP; e++) if (acc[e] > v0) { v0 = acc[e]; i0 = e; }
        int i1 = -1; float v1 = -3.4e38f;
#pragma unroll
        for (int e = 0; e < NEXP; e++) if (e != i0 && acc[e] > v1) { v1 = acc[e]; i1 = e; }
        float g0 = 1.f / (1.f + expf(v1 - v0));   // softmax over top-2 (v0 >= v1)
        tok_e[t * 2] = i0; tok_e[t * 2 + 1] = i1;
        tok_g[t * 2] = g0; tok_g[t * 2 + 1] = 1.f - g0;
    }
}

// ---------------------------------------------------------------------------
// r8: build lists with 8 PARALLEL blocks (one expert each) + wfc cast arm.
// The r0-r7 single-block version issued ~16k scattered stores from ONE CU
// (~27-53 us of serial store latency by the cycle model); per-expert blocks
// cut that 8x and keep the slot order (token order within expert) BIT-
// IDENTICAL. Blocks 8..1031 stream-cast wfc -> bf16 (needed first by GEMM1,
// next dispatch), overlapping the cast with the scan instead of serializing
// it ahead of gating (old cast_gate).
__global__ __launch_bounds__(1024) void build_cast(
    const int* __restrict__ tok_e, const float* __restrict__ tok_g,
    int* __restrict__ counts,
    int* __restrict__ entries, float* __restrict__ gates,
    const float* __restrict__ wfc, unsigned short* __restrict__ wfc_bf, int n4)
{
    if (blockIdx.x >= 8) {
        // ---- wfc cast arm (1024 blocks x 1024 thr)
        int stride = 1024 * 1024;
        for (int i = (int)(blockIdx.x - 8) * 1024 + threadIdx.x; i < n4; i += stride)
            cast4(wfc, wfc_bf, i);
        return;
    }
    // ---- scan arm: this block owns expert e
    int e = blockIdx.x;
    __shared__ unsigned wtot[16], wbase[16];
    int tid = threadIdx.x;
    int lane = tid & 63, wid = tid >> 6;

    int eL[8]; float gL[8];
    int4 ea = ((const int4*)tok_e)[tid * 2];
    int4 eb = ((const int4*)tok_e)[tid * 2 + 1];
    float4 ga = ((const float4*)tok_g)[tid * 2];
    float4 gb = ((const float4*)tok_g)[tid * 2 + 1];
    eL[0] = ea.x; eL[1] = ea.y; eL[2] = ea.z; eL[3] = ea.w;
    eL[4] = eb.x; eL[5] = eb.y; eL[6] = eb.z; eL[7] = eb.w;
    gL[0] = ga.x; gL[1] = ga.y; gL[2] = ga.z; gL[3] = ga.w;
    gL[4] = gb.x; gL[5] = gb.y; gL[6] = gb.z; gL[7] = gb.w;

    unsigned m = 0, cnt = 0;
#pragma unroll
    for (int j = 0; j < 8; j++)
        if (eL[j] == e) { m |= 1u << j; cnt++; }

    unsigned il = cnt;                       // inclusive wave scan
#pragma unroll
    for (int s = 1; s < 64; s <<= 1) {
        unsigned t1 = __shfl_up(il, s);
        if (lane >= s) il += t1;
    }
    if (lane == 63) wtot[wid] = il;
    __syncthreads();
    if (tid == 0) {
        unsigned r = 0;
#pragma unroll
        for (int i = 0; i < 16; i++) { unsigned a = wtot[i]; wbase[i] = r; r += a; }
        counts[e] = (int)r;
    }
    __syncthreads();
    unsigned slot = wbase[wid] + (il - cnt); // exclusive thread prefix
#pragma unroll
    for (int j = 0; j < 8; j++) {
        if (m & (1u << j)) {
            entries[e * TOKENS + slot] = tid * 8 + j;   // = t*2+k
            gates[e * TOKENS + slot]   = gL[j];
            slot++;
        }
    }
}

// ---------------------------------------------------------------------------
// Routed GEMM, r8 = r5-proven configs restored (the r6/r7 variants all
// regressed: BK32-dbuf 55us, TN256 spilled at VGPR 128 / +17MB scratch
// writes). BM=256, 8 waves (4x2).
//   GEMM1 (IS_FC, DBUF=false): TN=128, single-buffer drain-0 K-loop,
//     48KB LDS -> 3 blk/CU; grid 768 GEMM blocks (~384 active, single
//     span) + 512 CAST blocks that stream wproj -> bf16 (needed only by
//     GEMM2, the NEXT dispatch — stream order guarantees completion) in
//     the slots early-exit blocks vacate. Proven 51.2 us + small contention.
//   GEMM2 (DBUF=true): TN=64, T4 counted-vmcnt double-buffer (raw
//     s_barrier + s_waitcnt vmcnt(5), never 0 in-loop), 80KB -> 2 blk/CU.
//     r5's censored-good config (<=50.8 us).
// LDS rows 128B = 8x16B segs, XOR swizzle seg^(row&7): ds_read_b128
// bank-uniform, 0 conflicts (verified r6). Geometry from counts[8];
// bucket == expert (XCD-affine under round-robin dispatch).
template<int KD, int ND, int TN, int NCTP, int GG, bool IS_FC, bool DBUF>
__global__ __launch_bounds__(512) void moe_gemm(
    const unsigned short* __restrict__ Asrc,
    const unsigned short* __restrict__ Bsrc,    // [E][ND][KD] (B^T form)
    const int* __restrict__ counts,
    const int* __restrict__ entries,
    const float* __restrict__ gates,
    unsigned short* __restrict__ hmid,
    float* __restrict__ outp,
    const float* __restrict__ castS, unsigned short* __restrict__ castD, int castN4)
{
    if constexpr (IS_FC) {
        if (blockIdx.x >= GG) {     // ---- wproj cast arm (512 blocks x 512 thr)
            int stride = 512 * 512;
            for (int i = (int)(blockIdx.x - GG) * 512 + threadIdx.x; i < castN4; i += stride)
                cast4(castS, castD, i);
            return;
        }
    }
    constexpr int BM = 256;
    constexpr int SLOTS = GG / 8;
    constexpr int AJ = TN / 32;        // col frags per wave (4 or 2)
    constexpr int CB = TN / 64;        // B staging calls per wave (2 or 1)
    constexpr int NV = 4 + CB;         // gload_lds per wave per stage
    int bkt  = blockIdx.x & 7;         // bucket == expert
    int slot = blockIdx.x >> 3;        // 0..SLOTS-1

    // early exit needs only this bucket's count (exiters vacate for casts)
    int n_e = counts[bkt];
    int rts = (n_e + BM - 1) >> 8;
    int nfill = rts * NCTP;
    if (slot >= nfill) return;
    int ebase = 0;
#pragma unroll
    for (int e = 0; e < NEXP; e++) { int c = counts[e]; if (e < bkt) ebase += c; }
    const int* lst = entries + bkt * TOKENS;

    int tid = threadIdx.x;
    int w = tid >> 6;          // wave 0..7
    int l = tid & 63;          // lane
    int sg = l & 7;
    int lr8 = l >> 3;          // row-within-8 staged by this lane
    int lo = l & 15;
    int q  = l >> 4;
    int wr = w >> 1, wc = w & 1;   // 4x2 wave grid: 64 rows x TN/2 cols each

    __shared__ __align__(16) unsigned short sA[(DBUF ? 2 : 1) * BM * 64];
    __shared__ __align__(16) unsigned short sB[(DBUF ? 2 : 1) * TN * 64];
    unsigned short* sA0 = sA;
    unsigned short* sA1 = sA + BM * 64;   // compile-time offsets (static alias)
    unsigned short* sB0 = sB;
    unsigned short* sB1 = sB + TN * 64;

    // fragment LDS offsets (item-independent)
    int aOff[4][2], bOff[AJ][2];
#pragma unroll
    for (int i = 0; i < 4; i++) {
        int m = wr * 64 + i * 16 + lo;
#pragma unroll
        for (int s = 0; s < 2; s++)
            aOff[i][s] = m * 64 + ((s * 4 + q) ^ (m & 7)) * 8;
    }
#pragma unroll
    for (int j = 0; j < AJ; j++) {
        int n = wc * (TN / 2) + j * 16 + lo;
#pragma unroll
        for (int s = 0; s < 2; s++)
            bOff[j][s] = n * 64 + ((s * 4 + q) ^ (n & 7)) * 8;
    }

    for (int p = slot; p < nfill; p += SLOTS) {   // backstop stride; 1 iter typical
        int ct   = p / rts;
        int r    = p - ct * rts;
        int row0 = r << 8;
        int n0 = ct * TN;

        // ---- staging addresses: rows are 128B (64 shorts), 8 segs of 16B.
        // A call covers 8 rows (64 lanes x 16B = 1KB). Global K-seg for
        // (row rr, LDS seg sg) is sg ^ (rr&7). Wave w stages A rows
        // [w*32, w*32+32) (4 calls) and B rows [w*(TN/8), ...) (CB calls).
        const unsigned short* Ag[4];
        int aLds[4];
#pragma unroll
        for (int c = 0; c < 4; c++) {
            int rr = w * 32 + c * 8 + lr8;       // tile row 0..255
            int gr = row0 + rr;
            int id = gr < n_e ? gr : n_e - 1;    // clamp (discarded in epilogue)
            size_t arow = IS_FC ? (size_t)(lst[id] >> 1) : (size_t)(ebase + id);
            Ag[c] = Asrc + arow * KD + (size_t)((sg ^ (rr & 7)) * 8);
            aLds[c] = (w * 32 + c * 8) * 64;     // wave-uniform chunk base
        }
        const unsigned short* Bg[CB];
        int bLds[CB];
#pragma unroll
        for (int c = 0; c < CB; c++) {
            int rr = w * (TN / 8) + c * 8 + lr8; // tile row 0..TN-1
            Bg[c] = Bsrc + ((size_t)bkt * ND + n0 + rr) * KD + (size_t)((sg ^ (rr & 7)) * 8);
            bLds[c] = (w * (TN / 8) + c * 8) * 64;
        }

        f32x4 acc[4][AJ];
#pragma unroll
        for (int i = 0; i < 4; i++)
#pragma unroll
            for (int j = 0; j < AJ; j++) acc[i][j] = (f32x4){0.f, 0.f, 0.f, 0.f};

        auto stage = [&](unsigned short* SA, unsigned short* SB, int k0) {
#pragma unroll
            for (int c = 0; c < 4; c++) gload_lds16(Ag[c] + k0, SA + aLds[c]);
#pragma unroll
            for (int c = 0; c < CB; c++) gload_lds16(Bg[c] + k0, SB + bLds[c]);
        };
        auto compute = [&](const unsigned short* SA, const unsigned short* SB) {
#pragma unroll
            for (int s = 0; s < 2; s++) {
                bf16x8 a[4], b[AJ];
#pragma unroll
                for (int i = 0; i < 4; i++) a[i] = *(const bf16x8*)(SA + aOff[i][s]);
#pragma unroll
                for (int j = 0; j < AJ; j++) b[j] = *(const bf16x8*)(SB + bOff[j][s]);
#pragma unroll
                for (int i = 0; i < 4; i++)
#pragma unroll
                    for (int j = 0; j < AJ; j++)
                        acc[i][j] = __builtin_amdgcn_mfma_f32_16x16x32_bf16(a[i], b[j], acc[i][j], 0, 0, 0);
            }
        };

        if constexpr (!DBUF) {
            // single-buffer, drain-0 __syncthreads loop (r5 control, 51.2us)
            for (int k0 = 0; k0 < KD; k0 += 64) {
                stage(sA0, sB0, k0);
                __syncthreads();                // drains vmcnt (compiler-inserted)
                compute(sA0, sB0);
                __syncthreads();                // protect LDS before next staging
            }
        } else {
            // T4 counted-vmcnt double-buffer, raw barriers; vmcnt(NV) retires
            // the older buffer's loads while the newest NV stay in flight.
#define WAITN asm volatile("s_waitcnt vmcnt(%0)" :: "n"(NV) : "memory")
#define WAIT0 asm volatile("s_waitcnt vmcnt(0)" ::: "memory")
            stage(sA0, sB0, 0);
            for (int k0 = 0; k0 < KD; k0 += 128) {   // KD/128 = 12 iters
                stage(sA1, sB1, k0 + 64);
                WAITN;
                __builtin_amdgcn_s_barrier();
                __builtin_amdgcn_s_setprio(1);
                compute(sA0, sB0);
                __builtin_amdgcn_s_setprio(0);
                __builtin_amdgcn_s_barrier();
                if (k0 + 128 < KD) {
                    stage(sA0, sB0, k0 + 128);
                    WAITN;
                } else {
                    WAIT0;
                }
                __builtin_amdgcn_s_barrier();
                __builtin_amdgcn_s_setprio(1);
                compute(sA1, sB1);
                __builtin_amdgcn_s_setprio(0);
                __builtin_amdgcn_s_barrier();
            }
#undef WAITN
#undef WAIT0
        }

        // ---- epilogue (D: col=lo, row=q*4+rr)
#pragma unroll
        for (int i = 0; i < 4; i++) {
            int rowB = row0 + wr * 64 + i * 16 + q * 4;
#pragma unroll
            for (int rr = 0; rr < 4; rr++) {
                int orow = rowB + rr;
                if (orow < n_e) {
                    if (IS_FC) {
                        size_t hrow = (size_t)(ebase + orow);
#pragma unroll
                        for (int j = 0; j < AJ; j++) {
                            float v = acc[i][j][rr];
                            v = 0.5f * v * (1.f + erff(v * 0.70710678118654752f));  // exact gelu
                            hmid[hrow * ND + n0 + wc * (TN / 2) + j * 16 + lo] = f2bf(v);
                        }
                    } else {
                        int token = lst[orow] >> 1;
                        float g = gates[bkt * TOKENS + orow];
#pragma unroll
                        for (int j = 0; j < AJ; j++) {
                            atomicAdd(&outp[(size_t)token * ND + n0 + wc * (TN / 2) + j * 16 + lo],
                                      acc[i][j][rr] * g);
                        }
                    }
                }
            }
        }
    }
}

// ---------------------------------------------------------------------------
extern "C" void kernel_launch(void* const* d_in, const int* in_sizes, int n_in,
                              void* d_out, int out_size, void* d_ws, size_t ws_size,
                              hipStream_t stream) {
    const float* x     = (const float*)d_in[0];   // [T, H]
    const float* gw    = (const float*)d_in[1];   // [E, H]
    const float* wfc   = (const float*)d_in[2];   // [E, FF, H]
    const float* wproj = (const float*)d_in[3];   // [E, H, FF]
    float* outp   = (float*)d_out;                       // [T*H]
    float* logits = outp + (size_t)TOKENS * HDIM;        // [T*E]

    char* ws = (char*)d_ws;
    int*   counts  = (int*)ws;                            // 8 ints
    size_t off = 256;
    int*   entries = (int*)(ws + off);                    // [E][T]
    float* gates   = (float*)(ws + off + NEXP * TOKENS * 4);
    off += 2ull * NEXP * TOKENS * 4;
    int*   tok_e   = (int*)(ws + off);   off += (size_t)TOKENS * 2 * 4;
    float* tok_g   = (float*)(ws + off); off += (size_t)TOKENS * 2 * 4;
    unsigned short* x_bf   = (unsigned short*)(ws + off); off += (size_t)TOKENS * HDIM * 2;
    unsigned short* wfc_bf = (unsigned short*)(ws + off); off += (size_t)NEXP * FFDIM * HDIM * 2;
    unsigned short* wpj_bf = (unsigned short*)(ws + off); off += (size_t)NEXP * HDIM * FFDIM * 2;
    unsigned short* hmid   = (unsigned short*)(ws + off);        // [2T][FF] bf16, slot-compacted

    gating<<<TOKENS / 4, 256, 0, stream>>>(x, gw, logits, tok_e, tok_g, x_bf, outp);
    build_cast<<<8 + 1024, 1024, 0, stream>>>(tok_e, tok_g, counts, entries, gates,
                                              wfc, wfc_bf, NEXP * FFDIM * HDIM / 4);
    moe_gemm<HDIM, FFDIM, 128, FFDIM / 128, 768, true,  false>
        <<<768 + 512, 512, 0, stream>>>(
        x_bf, wfc_bf, counts, entries, gates, hmid, outp,
        wproj, wpj_bf, NEXP * HDIM * FFDIM / 4);
    moe_gemm<FFDIM, HDIM, 64,  HDIM / 64,   512, false, true >
        <<<512, 512, 0, stream>>>(
        hmid, wpj_bf, counts, entries, gates, hmid, outp,
        nullptr, nullptr, 0);
}